// Round 1
// baseline (830.289 us; speedup 1.0000x reference)
//
#include <hip/hip_runtime.h>

typedef unsigned int u32;
typedef unsigned short u16;
typedef __attribute__((ext_vector_type(8))) short bf16x8;
typedef __attribute__((ext_vector_type(4))) float f32x4;

#define B_   2
#define S_   2048
#define H_   16
#define KVH_ 8
#define D_   128
#define HID_ 2048
#define IN_  4096

__device__ __forceinline__ float bf2f(short h) {
    return __builtin_bit_cast(float, (u32)((u16)h) << 16);
}
__device__ __forceinline__ u16 f2bf(float f) {
    u32 u = __builtin_bit_cast(u32, f);
    u += 0x7FFF + ((u >> 16) & 1);   // RNE
    return (u16)(u >> 16);
}

__device__ __forceinline__ void gl_lds16(const void* g, void* l) {
    __builtin_amdgcn_global_load_lds(
        (const __attribute__((address_space(1))) u32*)g,
        (__attribute__((address_space(3))) u32*)l, 16, 0, 0);
}

__device__ __forceinline__ f32x4 mfma16(bf16x8 a, bf16x8 b, f32x4 c) {
    return __builtin_amdgcn_mfma_f32_16x16x32_bf16(a, b, c, 0, 0, 0);
}

// ---------------- elementwise f32 -> bf16 convert (vectorized x4) ----------
__global__ void k_conv(const float* __restrict__ s, u16* __restrict__ d, int n4) {
    int i = blockIdx.x * 256 + threadIdx.x;
    if (i < n4) {
        float4 v = ((const float4*)s)[i];
        ushort4 o;
        o.x = f2bf(v.x); o.y = f2bf(v.y); o.z = f2bf(v.z); o.w = f2bf(v.w);
        ((ushort4*)d)[i] = o;
    }
}

// ---------------- cache_v[0] (B,H,S,D) f32 -> (B,H,D,S) bf16 ---------------
__global__ void k_vtrans(const float* __restrict__ src, u16* __restrict__ dst) {
    __shared__ float t[32][33];
    const int bh = blockIdx.z, d0 = blockIdx.y * 32, s0 = blockIdx.x * 32;
    const int tx = threadIdx.x & 31, ty = threadIdx.x >> 5;
    const float* sp = src + (size_t)bh * S_ * D_;
#pragma unroll
    for (int i = 0; i < 4; i++) {
        int sl = ty + i * 8;
        t[tx][sl] = sp[(size_t)(s0 + sl) * D_ + d0 + tx];
    }
    __syncthreads();
    u16* dp = dst + (size_t)bh * D_ * S_;
#pragma unroll
    for (int i = 0; i < 4; i++) {
        int dl = ty + i * 8;
        dp[(size_t)(d0 + dl) * S_ + s0 + tx] = f2bf(t[dl][tx]);
    }
}

// ---------------- RoPE in-place; Q also pre-scaled by 1/sqrt(D) ------------
__global__ void k_rope(u16* __restrict__ Q0, u16* __restrict__ Kn,
                       const float* __restrict__ cosp, const float* __restrict__ sinp) {
    int idx = blockIdx.x * 256 + threadIdx.x;
    const float scale = 0.08838834764831845f;  // 1/sqrt(128)
    if (idx < B_ * H_ * S_ * 64) {
        int d = idx & 63, s = (idx >> 6) & (S_ - 1), bh = idx >> 17;
        int b = bh >> 4;
        u16* base = Q0 + ((size_t)bh * S_ + s) * D_;
        size_t ci = ((size_t)(b * S_ + s)) * D_ + d;
        float c = cosp[ci], sn = sinp[ci];
        float x1 = bf2f((short)base[d]), x2 = bf2f((short)base[d + 64]);
        base[d]      = f2bf((x1 * c - x2 * sn) * scale);
        base[d + 64] = f2bf((x2 * c + x1 * sn) * scale);
    } else {
        int t2 = idx - B_ * H_ * S_ * 64;
        int d = t2 & 63, s = (t2 >> 6) & (S_ - 1), bh = t2 >> 17;  // b*KVH+kvh
        int b = bh >> 3;
        u16* base = Kn + ((size_t)bh * S_ + s) * D_;
        size_t ci = ((size_t)(b * S_ + s)) * D_ + d;
        float c = cosp[ci], sn = sinp[ci];
        float x1 = bf2f((short)base[d]), x2 = bf2f((short)base[d + 64]);
        base[d]      = f2bf(x1 * c - x2 * sn);
        base[d + 64] = f2bf(x2 * c + x1 * sn);
    }
}

// ---------------- bt-GEMM: C[m][n] = sum_k A[m][k]*Bm[n][k] ----------------
// EPI==0: write f32 C. EPI==1: scatter bf16 into Q0/Kn/Vn head-major layouts.
template <int EPI>
__global__ __launch_bounds__(256) void k_gemm(
    const u16* __restrict__ A, const u16* __restrict__ Bm,
    float* __restrict__ Cf, u16* __restrict__ q0p, u16* __restrict__ knp,
    u16* __restrict__ vnp, int M, int N, int K) {
    __shared__ __align__(16) u16 Ash[128 * 32];
    __shared__ __align__(16) u16 Bsh[128 * 32];
    const int tid = threadIdx.x;
    const int w = tid >> 6, lane = tid & 63, quad = lane >> 4, l15 = lane & 15;
    const int m0 = blockIdx.y * 128, n0 = blockIdx.x * 128;
    const int wm = (w >> 1) * 64, wn = (w & 1) * 64;

    f32x4 acc[4][4];
#pragma unroll
    for (int i = 0; i < 4; i++)
#pragma unroll
        for (int j = 0; j < 4; j++) acc[i][j] = (f32x4){0.f, 0.f, 0.f, 0.f};

    // staging assignment (16B pieces, XOR-swizzled k-chunk within each row)
    int pA = tid, pB = tid + 256;
    int ar0 = pA >> 2, akc0 = (pA & 3) ^ ((ar0 >> 1) & 3);
    int ar1 = pB >> 2, akc1 = (pB & 3) ^ ((ar1 >> 1) & 3);
    const u16* Ag0 = A + (size_t)(m0 + ar0) * K + akc0 * 8;
    const u16* Ag1 = A + (size_t)(m0 + ar1) * K + akc1 * 8;
    const u16* Bg0 = Bm + (size_t)(n0 + ar0) * K + akc0 * 8;
    const u16* Bg1 = Bm + (size_t)(n0 + ar1) * K + akc1 * 8;
    u16* lA0 = Ash + (w * 64) * 8;
    u16* lA1 = Ash + (256 + w * 64) * 8;
    u16* lB0 = Bsh + (w * 64) * 8;
    u16* lB1 = Bsh + (256 + w * 64) * 8;

    for (int k0 = 0; k0 < K; k0 += 32) {
        gl_lds16(Ag0 + k0, lA0);
        gl_lds16(Ag1 + k0, lA1);
        gl_lds16(Bg0 + k0, lB0);
        gl_lds16(Bg1 + k0, lB1);
        __syncthreads();
        bf16x8 af[4], bfr[4];
#pragma unroll
        for (int mi = 0; mi < 4; mi++) {
            int m = wm + mi * 16 + l15;
            af[mi] = *(const bf16x8*)(Ash + (m * 4 + (quad ^ ((m >> 1) & 3))) * 8);
        }
#pragma unroll
        for (int ni = 0; ni < 4; ni++) {
            int n = wn + ni * 16 + l15;
            bfr[ni] = *(const bf16x8*)(Bsh + (n * 4 + (quad ^ ((n >> 1) & 3))) * 8);
        }
#pragma unroll
        for (int mi = 0; mi < 4; mi++)
#pragma unroll
            for (int ni = 0; ni < 4; ni++)
                acc[mi][ni] = mfma16(af[mi], bfr[ni], acc[mi][ni]);
        __syncthreads();
    }

    if constexpr (EPI == 0) {
#pragma unroll
        for (int mi = 0; mi < 4; mi++)
#pragma unroll
            for (int ni = 0; ni < 4; ni++) {
                int nn = n0 + wn + ni * 16 + l15;
#pragma unroll
                for (int reg = 0; reg < 4; reg++) {
                    int mm = m0 + wm + mi * 16 + quad * 4 + reg;
                    Cf[(size_t)mm * N + nn] = acc[mi][ni][reg];
                }
            }
    } else {
#pragma unroll
        for (int mi = 0; mi < 4; mi++)
#pragma unroll
            for (int ni = 0; ni < 4; ni++) {
                int nn = n0 + wn + ni * 16 + l15;
#pragma unroll
                for (int reg = 0; reg < 4; reg++) {
                    int mm = m0 + wm + mi * 16 + quad * 4 + reg;
                    int bb = mm >> 11, ss = mm & (S_ - 1);
                    u16 val = f2bf(acc[mi][ni][reg]);
                    if (nn < 2048) {
                        q0p[(((size_t)(bb * H_ + (nn >> 7))) * S_ + ss) * D_ + (nn & 127)] = val;
                    } else if (nn < 3072) {
                        knp[(((size_t)(bb * KVH_ + ((nn - 2048) >> 7))) * S_ + ss) * D_ + (nn & 127)] = val;
                    } else {
                        vnp[(((size_t)(bb * KVH_ + ((nn - 3072) >> 7))) * S_ + ss) * D_ + (nn & 127)] = val;
                    }
                }
            }
    }
}

// ---------------- flash attention + 3 diagonal extra keys ------------------
__global__ __launch_bounds__(256) void k_attn(
    const u16* __restrict__ Q0, const u16* __restrict__ K0c, const u16* __restrict__ V0T,
    const u16* __restrict__ Kn, const u16* __restrict__ Vn,
    const float* __restrict__ ck, const float* __restrict__ cv,
    u16* __restrict__ AO) {
    __shared__ __align__(16) u16 Ksh[4096];    // 32 j x 128 d, swizzled 16B pieces
    __shared__ __align__(16) u16 VTsh[4096];   // 128 d x 32 j, swizzled
    __shared__ __align__(16) u16 Psh[4 * 16 * 40];  // per-wave 16 x 32, stride 40
    __shared__ float esh[4 * 48];
    const int tid = threadIdx.x, w = tid >> 6, lane = tid & 63;
    const int quad = lane >> 4, l15 = lane & 15;
    const int b = blockIdx.z, h = blockIdx.y, q0 = blockIdx.x * 64;
    const int bh = b * H_ + h;
    const size_t kbase = (size_t)bh * S_ * D_;

    bf16x8 qf[4];
    {
        const u16* qp = Q0 + kbase + (size_t)(q0 + w * 16 + l15) * D_;
#pragma unroll
        for (int t = 0; t < 4; t++) qf[t] = *(const bf16x8*)(qp + t * 32 + quad * 8);
    }
    f32x4 Ot[8];
#pragma unroll
    for (int t = 0; t < 8; t++) Ot[t] = (f32x4){0.f, 0.f, 0.f, 0.f};
    float mrow[4] = {-1e30f, -1e30f, -1e30f, -1e30f};
    float lrow[4] = {0.f, 0.f, 0.f, 0.f};

    int pA = tid, pB = tid + 256;
    int kj0 = pA >> 4, kc0 = (pA & 15) ^ ((kj0 >> 1) & 7);
    int kj1 = pB >> 4, kc1 = (pB & 15) ^ ((kj1 >> 1) & 7);
    int vd0 = pA >> 2, vq0 = (pA & 3) ^ ((vd0 >> 1) & 3);
    int vd1 = pB >> 2, vq1 = (pB & 3) ^ ((vd1 >> 1) & 3);
    const u16* kg0 = K0c + kbase + (size_t)kj0 * D_ + kc0 * 8;
    const u16* kg1 = K0c + kbase + (size_t)kj1 * D_ + kc1 * 8;
    const u16* vg0 = V0T + kbase + (size_t)vd0 * S_ + vq0 * 8;
    const u16* vg1 = V0T + kbase + (size_t)vd1 * S_ + vq1 * 8;
    u16* lk0 = Ksh + (w * 64) * 8;
    u16* lk1 = Ksh + (256 + w * 64) * 8;
    u16* lv0 = VTsh + (w * 64) * 8;
    u16* lv1 = VTsh + (256 + w * 64) * 8;

    const int ntiles = (q0 >> 5) + 2;
    for (int jt = 0; jt < ntiles; ++jt) {
        const int j0 = jt * 32;
        gl_lds16(kg0 + (size_t)j0 * D_, lk0);
        gl_lds16(kg1 + (size_t)j0 * D_, lk1);
        gl_lds16(vg0 + j0, lv0);
        gl_lds16(vg1 + j0, lv1);
        __syncthreads();

        f32x4 s0 = (f32x4){0.f, 0.f, 0.f, 0.f}, s1 = (f32x4){0.f, 0.f, 0.f, 0.f};
#pragma unroll
        for (int t = 0; t < 4; t++) {
            int kc = t * 4 + quad;
            bf16x8 k0f = *(const bf16x8*)(Ksh + (l15 * 16 + (kc ^ ((l15 >> 1) & 7))) * 8);
            int j1i = l15 + 16;
            bf16x8 k1f = *(const bf16x8*)(Ksh + (j1i * 16 + (kc ^ ((j1i >> 1) & 7))) * 8);
            s0 = mfma16(qf[t], k0f, s0);
            s1 = mfma16(qf[t], k1f, s1);
        }
        if (j0 + 31 > q0 + w * 16) {  // causal mask on diagonal-crossing tiles
#pragma unroll
            for (int reg = 0; reg < 4; reg++) {
                int r = q0 + w * 16 + quad * 4 + reg;
                if (j0 + l15 > r) s0[reg] = -1e30f;
                if (j0 + 16 + l15 > r) s1[reg] = -1e30f;
            }
        }
        float pr0[4], pr1[4], alpha[4];
#pragma unroll
        for (int reg = 0; reg < 4; reg++) {
            float tm = fmaxf(s0[reg], s1[reg]);
            tm = fmaxf(tm, __shfl_xor(tm, 1));
            tm = fmaxf(tm, __shfl_xor(tm, 2));
            tm = fmaxf(tm, __shfl_xor(tm, 4));
            tm = fmaxf(tm, __shfl_xor(tm, 8));
            float mn = fmaxf(mrow[reg], tm);
            alpha[reg] = __expf(mrow[reg] - mn);
            mrow[reg] = mn;
            pr0[reg] = __expf(s0[reg] - mn);
            pr1[reg] = __expf(s1[reg] - mn);
            float rs = pr0[reg] + pr1[reg];
            rs += __shfl_xor(rs, 1);
            rs += __shfl_xor(rs, 2);
            rs += __shfl_xor(rs, 4);
            rs += __shfl_xor(rs, 8);
            lrow[reg] = lrow[reg] * alpha[reg] + rs;
        }
#pragma unroll
        for (int t = 0; t < 8; t++)
#pragma unroll
            for (int reg = 0; reg < 4; reg++) Ot[t][reg] *= alpha[reg];

        // P: C-layout -> LDS -> A-fragment layout (padded stride 40 elems)
        u16* pb = Psh + w * 640;
#pragma unroll
        for (int reg = 0; reg < 4; reg++) {
            int r = quad * 4 + reg;
            pb[r * 40 + l15] = f2bf(pr0[reg]);
            pb[r * 40 + 16 + l15] = f2bf(pr1[reg]);
        }
        bf16x8 pa = *(const bf16x8*)(pb + l15 * 40 + quad * 8);
#pragma unroll
        for (int t = 0; t < 8; t++) {
            int d = t * 16 + l15;
            bf16x8 vb = *(const bf16x8*)(VTsh + (d * 4 + (quad ^ ((d >> 1) & 3))) * 8);
            Ot[t] = mfma16(pa, vb, Ot[t]);
        }
        __syncthreads();
    }

    // ---- extras: 3 diagonal keys/values per row ----
    const int srow_a = q0 + w * 16 + l15;  // A-layout row of this lane
    float ev[3];
#pragma unroll
    for (int c = 0; c < 2; c++) {
        const float* kp = ck + ((size_t)((1 + c) * B_ + b) * H_ + h) * S_ * D_ + (size_t)srow_a * D_;
        float part = 0.f;
#pragma unroll
        for (int t = 0; t < 4; t++) {
            int dbase = t * 32 + quad * 8;
            float4 v0 = *(const float4*)(kp + dbase);
            float4 v1 = *(const float4*)(kp + dbase + 4);
            part += bf2f(qf[t][0]) * v0.x + bf2f(qf[t][1]) * v0.y +
                    bf2f(qf[t][2]) * v0.z + bf2f(qf[t][3]) * v0.w;
            part += bf2f(qf[t][4]) * v1.x + bf2f(qf[t][5]) * v1.y +
                    bf2f(qf[t][6]) * v1.z + bf2f(qf[t][7]) * v1.w;
        }
        part += __shfl_xor(part, 16);
        part += __shfl_xor(part, 32);
        ev[c] = part;
    }
    {
        const u16* kp = Kn + ((size_t)(b * KVH_ + (h >> 1)) * S_ + srow_a) * D_;
        float part = 0.f;
#pragma unroll
        for (int t = 0; t < 4; t++) {
            bf16x8 kv = *(const bf16x8*)(kp + t * 32 + quad * 8);
#pragma unroll
            for (int i = 0; i < 8; i++) part += bf2f(qf[t][i]) * bf2f(kv[i]);
        }
        part += __shfl_xor(part, 16);
        part += __shfl_xor(part, 32);
        ev[2] = part;
    }
    if (quad == 0) {
        esh[w * 48 + l15] = ev[0];
        esh[w * 48 + 16 + l15] = ev[1];
        esh[w * 48 + 32 + l15] = ev[2];
    }
    __syncthreads();

    float alr[4], w0r[4], w1r[4], w2r[4], invr[4];
#pragma unroll
    for (int reg = 0; reg < 4; reg++) {
        int r = quad * 4 + reg;
        float e0 = esh[w * 48 + r], e1 = esh[w * 48 + 16 + r], e2 = esh[w * 48 + 32 + r];
        float mn = fmaxf(fmaxf(mrow[reg], e0), fmaxf(e1, e2));
        alr[reg] = __expf(mrow[reg] - mn);
        w0r[reg] = __expf(e0 - mn);
        w1r[reg] = __expf(e1 - mn);
        w2r[reg] = __expf(e2 - mn);
        float lf = lrow[reg] * alr[reg] + w0r[reg] + w1r[reg] + w2r[reg];
        invr[reg] = 1.f / lf;
    }
    const float* v1p = cv + ((size_t)(B_ + b) * H_ + h) * S_ * D_;       // layer 1
    const float* v2p = cv + ((size_t)(2 * B_ + b) * H_ + h) * S_ * D_;   // layer 2
    const u16* vnp = Vn + ((size_t)(b * KVH_ + (h >> 1))) * S_ * D_;
#pragma unroll
    for (int t = 0; t < 8; t++) {
        int d = t * 16 + l15;
#pragma unroll
        for (int reg = 0; reg < 4; reg++) {
            int sr = q0 + w * 16 + quad * 4 + reg;
            float v1 = v1p[(size_t)sr * D_ + d];
            float v2 = v2p[(size_t)sr * D_ + d];
            float vn = bf2f((short)vnp[(size_t)sr * D_ + d]);
            float o = (Ot[t][reg] * alr[reg] + w0r[reg] * v1 + w1r[reg] * v2 + w2r[reg] * vn) * invr[reg];
            AO[((size_t)(b * S_ + sr)) * HID_ + h * D_ + d] = f2bf(o);
        }
    }
}

// ---------------------------------------------------------------------------
extern "C" void kernel_launch(void* const* d_in, const int* in_sizes, int n_in,
                              void* d_out, int out_size, void* d_ws, size_t ws_size,
                              hipStream_t stream) {
    const float* hs      = (const float*)d_in[0];
    const float* cosp    = (const float*)d_in[2];
    const float* sinp    = (const float*)d_in[3];
    const float* cache_k = (const float*)d_in[4];
    const float* cache_v = (const float*)d_in[5];
    const float* Wq      = (const float*)d_in[6];
    const float* Wk      = (const float*)d_in[7];
    const float* Wv      = (const float*)d_in[8];
    const float* Wo      = (const float*)d_in[9];
    float* out = (float*)d_out;

    u16* ws = (u16*)d_ws;
    // Region A (32MB): X16 [conv->gemm1], then AO [attn->gemm2]
    u16* X16  = ws;
    u16* AO   = ws;
    // Region B (32MB): Wqkv16 [conv->gemm1], then K0c + V0T [conv->attn]
    u16* Wqkv = ws + 16777216;
    u16* K0c  = ws + 16777216;
    u16* V0T  = ws + 25165824;
    u16* Wo16 = ws + 33554432;  // 8MB
    u16* Q0   = ws + 37748736;  // 16MB
    u16* Kn   = ws + 46137344;  // 8MB
    u16* Vn   = ws + 50331648;  // 8MB

    // conversions
    k_conv<<<16384, 256, 0, stream>>>(hs, X16, 4194304);
    k_conv<<<8192, 256, 0, stream>>>(Wq, Wqkv, 2097152);
    k_conv<<<4096, 256, 0, stream>>>(Wk, Wqkv + 8388608, 1048576);
    k_conv<<<4096, 256, 0, stream>>>(Wv, Wqkv + 12582912, 1048576);
    k_conv<<<4096, 256, 0, stream>>>(Wo, Wo16, 1048576);

    // QKV projection with head-major scatter epilogue
    k_gemm<1><<<dim3(32, 32), 256, 0, stream>>>(X16, Wqkv, nullptr, Q0, Kn, Vn,
                                                4096, 4096, 4096);
    // RoPE (Q pre-scaled by 1/sqrt(D))
    k_rope<<<24576, 256, 0, stream>>>(Q0, Kn, cosp, sinp);

    // cache layer-0 conversions (into region B, now dead)
    k_conv<<<8192, 256, 0, stream>>>(cache_k, K0c, 2097152);
    k_vtrans<<<dim3(64, 4, 32), 256, 0, stream>>>(cache_v, V0T);

    // flash attention + extras
    k_attn<<<dim3(32, 16, 2), 256, 0, stream>>>(Q0, K0c, V0T, Kn, Vn,
                                                cache_k, cache_v, AO);
    // output projection
    k_gemm<0><<<dim3(16, 32), 256, 0, stream>>>(AO, Wo16, out, nullptr, nullptr,
                                                nullptr, 4096, 2048, 2048);
}

// Round 2
// 713.635 us; speedup vs baseline: 1.1635x; 1.1635x over previous
//
#include <hip/hip_runtime.h>

typedef unsigned int u32;
typedef unsigned short u16;
typedef __attribute__((ext_vector_type(8))) short bf16x8;
typedef __attribute__((ext_vector_type(4))) float f32x4;

#define B_   2
#define S_   2048
#define H_   16
#define KVH_ 8
#define D_   128
#define HID_ 2048
#define IN_  4096

__device__ __forceinline__ float bf2f(short h) {
    return __builtin_bit_cast(float, (u32)((u16)h) << 16);
}
__device__ __forceinline__ u16 f2bf(float f) {
    u32 u = __builtin_bit_cast(u32, f);
    u += 0x7FFF + ((u >> 16) & 1);   // RNE
    return (u16)(u >> 16);
}

__device__ __forceinline__ void gl_lds16(const void* g, void* l) {
    __builtin_amdgcn_global_load_lds(
        (const __attribute__((address_space(1))) u32*)g,
        (__attribute__((address_space(3))) u32*)l, 16, 0, 0);
}

__device__ __forceinline__ f32x4 mfma16(bf16x8 a, bf16x8 b, f32x4 c) {
    return __builtin_amdgcn_mfma_f32_16x16x32_bf16(a, b, c, 0, 0, 0);
}

// ---------------- elementwise f32 -> bf16 convert (vectorized x4) ----------
__global__ void k_conv(const float* __restrict__ s, u16* __restrict__ d, int n4) {
    int i = blockIdx.x * 256 + threadIdx.x;
    if (i < n4) {
        float4 v = ((const float4*)s)[i];
        ushort4 o;
        o.x = f2bf(v.x); o.y = f2bf(v.y); o.z = f2bf(v.z); o.w = f2bf(v.w);
        ((ushort4*)d)[i] = o;
    }
}

// ---------------- merged weight conversions (Wq|Wk|Wv|Wo) ------------------
__global__ void k_convw(const float* __restrict__ wq, const float* __restrict__ wk,
                        const float* __restrict__ wv, const float* __restrict__ wo,
                        u16* __restrict__ dq, u16* __restrict__ dk,
                        u16* __restrict__ dv, u16* __restrict__ dwo) {
    int i = blockIdx.x * 256 + threadIdx.x;  // float4 index, total 5242880
    const float* s; u16* d; int off;
    if (i < 2097152)      { s = wq; d = dq;  off = i; }
    else if (i < 3145728) { s = wk; d = dk;  off = i - 2097152; }
    else if (i < 4194304) { s = wv; d = dv;  off = i - 3145728; }
    else                  { s = wo; d = dwo; off = i - 4194304; }
    float4 v = ((const float4*)s)[off];
    ushort4 o;
    o.x = f2bf(v.x); o.y = f2bf(v.y); o.z = f2bf(v.z); o.w = f2bf(v.w);
    ((ushort4*)d)[off] = o;
}

// ---------------- cache_v[0] (B,H,S,D) f32 -> (B,H,D,S) bf16 ---------------
__global__ void k_vtrans(const float* __restrict__ src, u16* __restrict__ dst) {
    __shared__ float t[32][33];
    const int bh = blockIdx.z, d0 = blockIdx.y * 32, s0 = blockIdx.x * 32;
    const int tx = threadIdx.x & 31, ty = threadIdx.x >> 5;
    const float* sp = src + (size_t)bh * S_ * D_;
#pragma unroll
    for (int i = 0; i < 4; i++) {
        int sl = ty + i * 8;
        t[tx][sl] = sp[(size_t)(s0 + sl) * D_ + d0 + tx];
    }
    __syncthreads();
    u16* dp = dst + (size_t)bh * D_ * S_;
#pragma unroll
    for (int i = 0; i < 4; i++) {
        int dl = ty + i * 8;
        dp[(size_t)(d0 + dl) * S_ + s0 + tx] = f2bf(t[dl][tx]);
    }
}

// ---------------- RoPE in-place; Q also pre-scaled by 1/sqrt(D) ------------
__global__ void k_rope(u16* __restrict__ Q0, u16* __restrict__ Kn,
                       const float* __restrict__ cosp, const float* __restrict__ sinp) {
    int idx = blockIdx.x * 256 + threadIdx.x;
    const float scale = 0.08838834764831845f;  // 1/sqrt(128)
    if (idx < B_ * H_ * S_ * 64) {
        int d = idx & 63, s = (idx >> 6) & (S_ - 1), bh = idx >> 17;
        int b = bh >> 4;
        u16* base = Q0 + ((size_t)bh * S_ + s) * D_;
        size_t ci = ((size_t)(b * S_ + s)) * D_ + d;
        float c = cosp[ci], sn = sinp[ci];
        float x1 = bf2f((short)base[d]), x2 = bf2f((short)base[d + 64]);
        base[d]      = f2bf((x1 * c - x2 * sn) * scale);
        base[d + 64] = f2bf((x2 * c + x1 * sn) * scale);
    } else {
        int t2 = idx - B_ * H_ * S_ * 64;
        int d = t2 & 63, s = (t2 >> 6) & (S_ - 1), bh = t2 >> 17;  // b*KVH+kvh
        int b = bh >> 3;
        u16* base = Kn + ((size_t)bh * S_ + s) * D_;
        size_t ci = ((size_t)(b * S_ + s)) * D_ + d;
        float c = cosp[ci], sn = sinp[ci];
        float x1 = bf2f((short)base[d]), x2 = bf2f((short)base[d + 64]);
        base[d]      = f2bf(x1 * c - x2 * sn);
        base[d + 64] = f2bf(x2 * c + x1 * sn);
    }
}

// ---------------- bt-GEMM: C[m][n] = sum_k A[m][k]*Bm[n][k] ----------------
// EPI==0: write f32 C. EPI==1: scatter bf16 into Q0/Kn/Vn head-major layouts.
template <int EPI>
__global__ __launch_bounds__(256) void k_gemm(
    const u16* __restrict__ A, const u16* __restrict__ Bm,
    float* __restrict__ Cf, u16* __restrict__ q0p, u16* __restrict__ knp,
    u16* __restrict__ vnp, int M, int N, int K) {
    __shared__ __align__(16) u16 Ash[128 * 32];
    __shared__ __align__(16) u16 Bsh[128 * 32];
    const int tid = threadIdx.x;
    const int w = tid >> 6, lane = tid & 63, quad = lane >> 4, l15 = lane & 15;
    // GROUP_M=8 swizzle: consecutive blocks share the same n-tile (B reuse in L2)
    const int lin = blockIdx.y * gridDim.x + blockIdx.x;
    const int gmsz = 8 * gridDim.x;
    const int grp = lin / gmsz, rem = lin % gmsz;
    const int m0 = (grp * 8 + (rem & 7)) * 128;
    const int n0 = (rem >> 3) * 128;
    const int wm = (w >> 1) * 64, wn = (w & 1) * 64;

    f32x4 acc[4][4];
#pragma unroll
    for (int i = 0; i < 4; i++)
#pragma unroll
        for (int j = 0; j < 4; j++) acc[i][j] = (f32x4){0.f, 0.f, 0.f, 0.f};

    // staging assignment (16B pieces, XOR-swizzled k-chunk within each row)
    int pA = tid, pB = tid + 256;
    int ar0 = pA >> 2, akc0 = (pA & 3) ^ ((ar0 >> 1) & 3);
    int ar1 = pB >> 2, akc1 = (pB & 3) ^ ((ar1 >> 1) & 3);
    const u16* Ag0 = A + (size_t)(m0 + ar0) * K + akc0 * 8;
    const u16* Ag1 = A + (size_t)(m0 + ar1) * K + akc1 * 8;
    const u16* Bg0 = Bm + (size_t)(n0 + ar0) * K + akc0 * 8;
    const u16* Bg1 = Bm + (size_t)(n0 + ar1) * K + akc1 * 8;
    u16* lA0 = Ash + (w * 64) * 8;
    u16* lA1 = Ash + (256 + w * 64) * 8;
    u16* lB0 = Bsh + (w * 64) * 8;
    u16* lB1 = Bsh + (256 + w * 64) * 8;

    for (int k0 = 0; k0 < K; k0 += 32) {
        gl_lds16(Ag0 + k0, lA0);
        gl_lds16(Ag1 + k0, lA1);
        gl_lds16(Bg0 + k0, lB0);
        gl_lds16(Bg1 + k0, lB1);
        __syncthreads();
        bf16x8 af[4], bfr[4];
#pragma unroll
        for (int mi = 0; mi < 4; mi++) {
            int m = wm + mi * 16 + l15;
            af[mi] = *(const bf16x8*)(Ash + (m * 4 + (quad ^ ((m >> 1) & 3))) * 8);
        }
#pragma unroll
        for (int ni = 0; ni < 4; ni++) {
            int n = wn + ni * 16 + l15;
            bfr[ni] = *(const bf16x8*)(Bsh + (n * 4 + (quad ^ ((n >> 1) & 3))) * 8);
        }
#pragma unroll
        for (int mi = 0; mi < 4; mi++)
#pragma unroll
            for (int ni = 0; ni < 4; ni++)
                acc[mi][ni] = mfma16(af[mi], bfr[ni], acc[mi][ni]);
        __syncthreads();
    }

    if constexpr (EPI == 0) {
#pragma unroll
        for (int mi = 0; mi < 4; mi++)
#pragma unroll
            for (int ni = 0; ni < 4; ni++) {
                int nn = n0 + wn + ni * 16 + l15;
#pragma unroll
                for (int reg = 0; reg < 4; reg++) {
                    int mm = m0 + wm + mi * 16 + quad * 4 + reg;
                    Cf[(size_t)mm * N + nn] = acc[mi][ni][reg];
                }
            }
    } else {
#pragma unroll
        for (int mi = 0; mi < 4; mi++)
#pragma unroll
            for (int ni = 0; ni < 4; ni++) {
                int nn = n0 + wn + ni * 16 + l15;
#pragma unroll
                for (int reg = 0; reg < 4; reg++) {
                    int mm = m0 + wm + mi * 16 + quad * 4 + reg;
                    int bb = mm >> 11, ss = mm & (S_ - 1);
                    u16 val = f2bf(acc[mi][ni][reg]);
                    if (nn < 2048) {
                        q0p[(((size_t)(bb * H_ + (nn >> 7))) * S_ + ss) * D_ + (nn & 127)] = val;
                    } else if (nn < 3072) {
                        knp[(((size_t)(bb * KVH_ + ((nn - 2048) >> 7))) * S_ + ss) * D_ + (nn & 127)] = val;
                    } else {
                        vnp[(((size_t)(bb * KVH_ + ((nn - 3072) >> 7))) * S_ + ss) * D_ + (nn & 127)] = val;
                    }
                }
            }
    }
}

// ---------------- flash attention + 3 diagonal extra keys ------------------
// Double-buffered K/V staging with raw s_waitcnt vmcnt(4)+s_barrier so the
// prefetch stays in flight across the barrier (AITER-style), longest-q0-first
// dispatch order, lane-partial l accumulation (one final reduction).
__global__ __launch_bounds__(256) void k_attn(
    const u16* __restrict__ Q0, const u16* __restrict__ K0c, const u16* __restrict__ V0T,
    const u16* __restrict__ Kn, const u16* __restrict__ Vn,
    const float* __restrict__ ck, const float* __restrict__ cv,
    u16* __restrict__ AO) {
    __shared__ __align__(16) u16 Ksh[2 * 4096];    // 2 bufs x (32 j x 128 d)
    __shared__ __align__(16) u16 VTsh[2 * 4096];   // 2 bufs x (128 d x 32 j)
    __shared__ __align__(16) u16 Psh[4 * 16 * 40]; // per-wave 16 x 32, stride 40
    __shared__ float esh[4 * 48];
    const int tid = threadIdx.x, w = tid >> 6, lane = tid & 63;
    const int quad = lane >> 4, l15 = lane & 15;
    const int b = blockIdx.x >> 4, h = blockIdx.x & 15;
    const int q0 = (31 - blockIdx.y) * 64;   // longest blocks dispatch first
    const int bh = b * H_ + h;
    const size_t kbase = (size_t)bh * S_ * D_;

    bf16x8 qf[4];
    {
        const u16* qp = Q0 + kbase + (size_t)(q0 + w * 16 + l15) * D_;
#pragma unroll
        for (int t = 0; t < 4; t++) qf[t] = *(const bf16x8*)(qp + t * 32 + quad * 8);
    }
    f32x4 Ot[8];
#pragma unroll
    for (int t = 0; t < 8; t++) Ot[t] = (f32x4){0.f, 0.f, 0.f, 0.f};
    float mrow[4] = {-1e30f, -1e30f, -1e30f, -1e30f};
    float lrow[4] = {0.f, 0.f, 0.f, 0.f};  // lane-partial (per 2 keys/lane)

    int pA = tid, pB = tid + 256;
    int kj0 = pA >> 4, kc0 = (pA & 15) ^ ((kj0 >> 1) & 7);
    int kj1 = pB >> 4, kc1 = (pB & 15) ^ ((kj1 >> 1) & 7);
    int vd0 = pA >> 2, vq0 = (pA & 3) ^ ((vd0 >> 1) & 3);
    int vd1 = pB >> 2, vq1 = (pB & 3) ^ ((vd1 >> 1) & 3);
    const u16* kg0 = K0c + kbase + (size_t)kj0 * D_ + kc0 * 8;
    const u16* kg1 = K0c + kbase + (size_t)kj1 * D_ + kc1 * 8;
    const u16* vg0 = V0T + kbase + (size_t)vd0 * S_ + vq0 * 8;
    const u16* vg1 = V0T + kbase + (size_t)vd1 * S_ + vq1 * 8;
    const int ofsA = w * 512, ofsB = 2048 + w * 512;  // per-wave LDS piece bases

    const int ntiles = (q0 >> 5) + 2;
    // prologue: stage tile 0 into buffer 0
    gl_lds16(kg0, Ksh + ofsA);
    gl_lds16(kg1, Ksh + ofsB);
    gl_lds16(vg0, VTsh + ofsA);
    gl_lds16(vg1, VTsh + ofsB);

    for (int jt = 0; jt < ntiles; ++jt) {
        const int cur = jt & 1;
        const u16* Kb = Ksh + cur * 4096;
        const u16* Vb = VTsh + cur * 4096;
        if (jt + 1 < ntiles) {
            const int nb = (cur ^ 1) * 4096;
            const size_t j1 = (size_t)(jt + 1) * 32;
            gl_lds16(kg0 + j1 * D_, Ksh + nb + ofsA);
            gl_lds16(kg1 + j1 * D_, Ksh + nb + ofsB);
            gl_lds16(vg0 + j1, VTsh + nb + ofsA);
            gl_lds16(vg1 + j1, VTsh + nb + ofsB);
            // wait only for CURRENT tile's 4 loads; keep the 4 prefetch in flight
            __asm__ volatile("s_waitcnt vmcnt(4)\n\ts_barrier" ::: "memory");
        } else {
            __asm__ volatile("s_waitcnt vmcnt(0)\n\ts_barrier" ::: "memory");
        }
        const int j0 = jt * 32;

        f32x4 s0 = (f32x4){0.f, 0.f, 0.f, 0.f}, s1 = (f32x4){0.f, 0.f, 0.f, 0.f};
#pragma unroll
        for (int t = 0; t < 4; t++) {
            int kc = t * 4 + quad;
            bf16x8 k0f = *(const bf16x8*)(Kb + (l15 * 16 + (kc ^ ((l15 >> 1) & 7))) * 8);
            int j1i = l15 + 16;
            bf16x8 k1f = *(const bf16x8*)(Kb + (j1i * 16 + (kc ^ ((j1i >> 1) & 7))) * 8);
            s0 = mfma16(qf[t], k0f, s0);
            s1 = mfma16(qf[t], k1f, s1);
        }
        if (j0 + 31 > q0 + w * 16) {  // causal mask on diagonal-crossing tiles
#pragma unroll
            for (int reg = 0; reg < 4; reg++) {
                int r = q0 + w * 16 + quad * 4 + reg;
                if (j0 + l15 > r) s0[reg] = -1e30f;
                if (j0 + 16 + l15 > r) s1[reg] = -1e30f;
            }
        }
        float pr0[4], pr1[4], alpha[4];
        int changed = 0;
#pragma unroll
        for (int reg = 0; reg < 4; reg++) {
            float tm = fmaxf(s0[reg], s1[reg]);
            tm = fmaxf(tm, __shfl_xor(tm, 1));
            tm = fmaxf(tm, __shfl_xor(tm, 2));
            tm = fmaxf(tm, __shfl_xor(tm, 4));
            tm = fmaxf(tm, __shfl_xor(tm, 8));
            if (tm > mrow[reg]) {
                changed = 1;
                alpha[reg] = __expf(mrow[reg] - tm);
                mrow[reg] = tm;
            } else {
                alpha[reg] = 1.f;
            }
            pr0[reg] = __expf(s0[reg] - mrow[reg]);
            pr1[reg] = __expf(s1[reg] - mrow[reg]);
            lrow[reg] = lrow[reg] * alpha[reg] + pr0[reg] + pr1[reg];
        }
        if (__any(changed)) {
#pragma unroll
            for (int t = 0; t < 8; t++)
#pragma unroll
                for (int reg = 0; reg < 4; reg++) Ot[t][reg] *= alpha[reg];
        }

        // P: C-layout -> LDS -> A-fragment layout (padded stride 40 elems)
        u16* pb = Psh + w * 640;
#pragma unroll
        for (int reg = 0; reg < 4; reg++) {
            int r = quad * 4 + reg;
            pb[r * 40 + l15] = f2bf(pr0[reg]);
            pb[r * 40 + 16 + l15] = f2bf(pr1[reg]);
        }
        bf16x8 pa = *(const bf16x8*)(pb + l15 * 40 + quad * 8);
#pragma unroll
        for (int t = 0; t < 8; t++) {
            int d = t * 16 + l15;
            bf16x8 vb = *(const bf16x8*)(Vb + (d * 4 + (quad ^ ((d >> 1) & 3))) * 8);
            Ot[t] = mfma16(pa, vb, Ot[t]);
        }
        // end-of-iter barrier WITHOUT vmcnt drain (prefetch stays in flight)
        __asm__ volatile("s_barrier" ::: "memory");
    }

    // final cross-lane reduction of l (deferred from per-tile)
    float lsum[4];
#pragma unroll
    for (int reg = 0; reg < 4; reg++) {
        float r = lrow[reg];
        r += __shfl_xor(r, 1);
        r += __shfl_xor(r, 2);
        r += __shfl_xor(r, 4);
        r += __shfl_xor(r, 8);
        lsum[reg] = r;
    }

    // ---- extras: 3 diagonal keys/values per row ----
    const int srow_a = q0 + w * 16 + l15;  // A-layout row of this lane
    float ev[3];
#pragma unroll
    for (int c = 0; c < 2; c++) {
        const float* kp = ck + ((size_t)((1 + c) * B_ + b) * H_ + h) * S_ * D_ + (size_t)srow_a * D_;
        float part = 0.f;
#pragma unroll
        for (int t = 0; t < 4; t++) {
            int dbase = t * 32 + quad * 8;
            float4 v0 = *(const float4*)(kp + dbase);
            float4 v1 = *(const float4*)(kp + dbase + 4);
            part += bf2f(qf[t][0]) * v0.x + bf2f(qf[t][1]) * v0.y +
                    bf2f(qf[t][2]) * v0.z + bf2f(qf[t][3]) * v0.w;
            part += bf2f(qf[t][4]) * v1.x + bf2f(qf[t][5]) * v1.y +
                    bf2f(qf[t][6]) * v1.z + bf2f(qf[t][7]) * v1.w;
        }
        part += __shfl_xor(part, 16);
        part += __shfl_xor(part, 32);
        ev[c] = part;
    }
    {
        const u16* kp = Kn + ((size_t)(b * KVH_ + (h >> 1)) * S_ + srow_a) * D_;
        float part = 0.f;
#pragma unroll
        for (int t = 0; t < 4; t++) {
            bf16x8 kv = *(const bf16x8*)(kp + t * 32 + quad * 8);
#pragma unroll
            for (int i = 0; i < 8; i++) part += bf2f(qf[t][i]) * bf2f(kv[i]);
        }
        part += __shfl_xor(part, 16);
        part += __shfl_xor(part, 32);
        ev[2] = part;
    }
    if (quad == 0) {
        esh[w * 48 + l15] = ev[0];
        esh[w * 48 + 16 + l15] = ev[1];
        esh[w * 48 + 32 + l15] = ev[2];
    }
    __syncthreads();

    float alr[4], w0r[4], w1r[4], w2r[4], invr[4];
#pragma unroll
    for (int reg = 0; reg < 4; reg++) {
        int r = quad * 4 + reg;
        float e0 = esh[w * 48 + r], e1 = esh[w * 48 + 16 + r], e2 = esh[w * 48 + 32 + r];
        float mn = fmaxf(fmaxf(mrow[reg], e0), fmaxf(e1, e2));
        alr[reg] = __expf(mrow[reg] - mn);
        w0r[reg] = __expf(e0 - mn);
        w1r[reg] = __expf(e1 - mn);
        w2r[reg] = __expf(e2 - mn);
        float lf = lsum[reg] * alr[reg] + w0r[reg] + w1r[reg] + w2r[reg];
        invr[reg] = 1.f / lf;
    }
    const float* v1p = cv + ((size_t)(B_ + b) * H_ + h) * S_ * D_;       // layer 1
    const float* v2p = cv + ((size_t)(2 * B_ + b) * H_ + h) * S_ * D_;   // layer 2
    const u16* vnp = Vn + ((size_t)(b * KVH_ + (h >> 1))) * S_ * D_;
#pragma unroll
    for (int t = 0; t < 8; t++) {
        int d = t * 16 + l15;
#pragma unroll
        for (int reg = 0; reg < 4; reg++) {
            int sr = q0 + w * 16 + quad * 4 + reg;
            float v1 = v1p[(size_t)sr * D_ + d];
            float v2 = v2p[(size_t)sr * D_ + d];
            float vn = bf2f((short)vnp[(size_t)sr * D_ + d]);
            float o = (Ot[t][reg] * alr[reg] + w0r[reg] * v1 + w1r[reg] * v2 + w2r[reg] * vn) * invr[reg];
            AO[((size_t)(b * S_ + sr)) * HID_ + h * D_ + d] = f2bf(o);
        }
    }
}

// ---------------------------------------------------------------------------
extern "C" void kernel_launch(void* const* d_in, const int* in_sizes, int n_in,
                              void* d_out, int out_size, void* d_ws, size_t ws_size,
                              hipStream_t stream) {
    const float* hs      = (const float*)d_in[0];
    const float* cosp    = (const float*)d_in[2];
    const float* sinp    = (const float*)d_in[3];
    const float* cache_k = (const float*)d_in[4];
    const float* cache_v = (const float*)d_in[5];
    const float* Wq      = (const float*)d_in[6];
    const float* Wk      = (const float*)d_in[7];
    const float* Wv      = (const float*)d_in[8];
    const float* Wo      = (const float*)d_in[9];
    float* out = (float*)d_out;

    u16* ws = (u16*)d_ws;
    // Region A (32MB): X16 [conv->gemm1], then AO [attn->gemm2]
    u16* X16  = ws;
    u16* AO   = ws;
    // Region B (32MB): Wqkv16 [conv->gemm1], then K0c + V0T [conv->attn]
    u16* Wqkv = ws + 16777216;
    u16* K0c  = ws + 16777216;
    u16* V0T  = ws + 25165824;
    u16* Wo16 = ws + 33554432;  // 8MB
    u16* Q0   = ws + 37748736;  // 16MB
    u16* Kn   = ws + 46137344;  // 8MB
    u16* Vn   = ws + 50331648;  // 8MB

    // conversions
    k_conv<<<16384, 256, 0, stream>>>(hs, X16, 4194304);
    k_convw<<<20480, 256, 0, stream>>>(Wq, Wk, Wv, Wo,
                                       Wqkv, Wqkv + 8388608, Wqkv + 12582912, Wo16);

    // QKV projection with head-major scatter epilogue
    k_gemm<1><<<dim3(32, 32), 256, 0, stream>>>(X16, Wqkv, nullptr, Q0, Kn, Vn,
                                                4096, 4096, 4096);
    // RoPE (Q pre-scaled by 1/sqrt(D))
    k_rope<<<24576, 256, 0, stream>>>(Q0, Kn, cosp, sinp);

    // cache layer-0 conversions (into region B, now dead)
    k_conv<<<8192, 256, 0, stream>>>(cache_k, K0c, 2097152);
    k_vtrans<<<dim3(64, 4, 32), 256, 0, stream>>>(cache_v, V0T);

    // flash attention + extras (x = bh, y = reversed q-block: longest first)
    k_attn<<<dim3(32, 32), 256, 0, stream>>>(Q0, K0c, V0T, Kn, Vn,
                                             cache_k, cache_v, AO);
    // output projection
    k_gemm<0><<<dim3(16, 32), 256, 0, stream>>>(AO, Wo16, out, nullptr, nullptr,
                                                nullptr, 4096, 2048, 2048);
}

// Round 3
// 668.540 us; speedup vs baseline: 1.2419x; 1.0675x over previous
//
#include <hip/hip_runtime.h>

typedef unsigned int u32;
typedef unsigned short u16;
typedef __attribute__((ext_vector_type(8))) short bf16x8;
typedef __attribute__((ext_vector_type(4))) float f32x4;

#define B_   2
#define S_   2048
#define H_   16
#define KVH_ 8
#define D_   128
#define HID_ 2048
#define IN_  4096

__device__ __forceinline__ float bf2f(short h) {
    return __builtin_bit_cast(float, (u32)((u16)h) << 16);
}
__device__ __forceinline__ u16 f2bf(float f) {
    u32 u = __builtin_bit_cast(u32, f);
    u += 0x7FFF + ((u >> 16) & 1);   // RNE
    return (u16)(u >> 16);
}

__device__ __forceinline__ void gl_lds16(const void* g, void* l) {
    __builtin_amdgcn_global_load_lds(
        (const __attribute__((address_space(1))) u32*)g,
        (__attribute__((address_space(3))) u32*)l, 16, 0, 0);
}

__device__ __forceinline__ f32x4 mfma16(bf16x8 a, bf16x8 b, f32x4 c) {
    return __builtin_amdgcn_mfma_f32_16x16x32_bf16(a, b, c, 0, 0, 0);
}

// ---------------- elementwise f32 -> bf16 convert (vectorized x4) ----------
__global__ void k_conv(const float* __restrict__ s, u16* __restrict__ d, int n4) {
    int i = blockIdx.x * 256 + threadIdx.x;
    if (i < n4) {
        float4 v = ((const float4*)s)[i];
        ushort4 o;
        o.x = f2bf(v.x); o.y = f2bf(v.y); o.z = f2bf(v.z); o.w = f2bf(v.w);
        ((ushort4*)d)[i] = o;
    }
}

// ---------------- merged weight conversions (Wq|Wk|Wv|Wo) ------------------
__global__ void k_convw(const float* __restrict__ wq, const float* __restrict__ wk,
                        const float* __restrict__ wv, const float* __restrict__ wo,
                        u16* __restrict__ dq, u16* __restrict__ dk,
                        u16* __restrict__ dv, u16* __restrict__ dwo) {
    int i = blockIdx.x * 256 + threadIdx.x;  // float4 index, total 5242880
    const float* s; u16* d; int off;
    if (i < 2097152)      { s = wq; d = dq;  off = i; }
    else if (i < 3145728) { s = wk; d = dk;  off = i - 2097152; }
    else if (i < 4194304) { s = wv; d = dv;  off = i - 3145728; }
    else                  { s = wo; d = dwo; off = i - 4194304; }
    float4 v = ((const float4*)s)[off];
    ushort4 o;
    o.x = f2bf(v.x); o.y = f2bf(v.y); o.z = f2bf(v.z); o.w = f2bf(v.w);
    ((ushort4*)d)[off] = o;
}

// ---------------- cache_v[0] (B,H,S,D) f32 -> (B,H,D,S) bf16 ---------------
__global__ void k_vtrans(const float* __restrict__ src, u16* __restrict__ dst) {
    __shared__ float t[32][33];
    const int bh = blockIdx.z, d0 = blockIdx.y * 32, s0 = blockIdx.x * 32;
    const int tx = threadIdx.x & 31, ty = threadIdx.x >> 5;
    const float* sp = src + (size_t)bh * S_ * D_;
#pragma unroll
    for (int i = 0; i < 4; i++) {
        int sl = ty + i * 8;
        t[tx][sl] = sp[(size_t)(s0 + sl) * D_ + d0 + tx];
    }
    __syncthreads();
    u16* dp = dst + (size_t)bh * D_ * S_;
#pragma unroll
    for (int i = 0; i < 4; i++) {
        int dl = ty + i * 8;
        dp[(size_t)(d0 + dl) * S_ + s0 + tx] = f2bf(t[dl][tx]);
    }
}

// ---------------- RoPE in-place; Q also pre-scaled by 1/sqrt(D) ------------
__global__ void k_rope(u16* __restrict__ Q0, u16* __restrict__ Kn,
                       const float* __restrict__ cosp, const float* __restrict__ sinp) {
    int idx = blockIdx.x * 256 + threadIdx.x;
    const float scale = 0.08838834764831845f;  // 1/sqrt(128)
    if (idx < B_ * H_ * S_ * 64) {
        int d = idx & 63, s = (idx >> 6) & (S_ - 1), bh = idx >> 17;
        int b = bh >> 4;
        u16* base = Q0 + ((size_t)bh * S_ + s) * D_;
        size_t ci = ((size_t)(b * S_ + s)) * D_ + d;
        float c = cosp[ci], sn = sinp[ci];
        float x1 = bf2f((short)base[d]), x2 = bf2f((short)base[d + 64]);
        base[d]      = f2bf((x1 * c - x2 * sn) * scale);
        base[d + 64] = f2bf((x2 * c + x1 * sn) * scale);
    } else {
        int t2 = idx - B_ * H_ * S_ * 64;
        int d = t2 & 63, s = (t2 >> 6) & (S_ - 1), bh = t2 >> 17;  // b*KVH+kvh
        int b = bh >> 3;
        u16* base = Kn + ((size_t)bh * S_ + s) * D_;
        size_t ci = ((size_t)(b * S_ + s)) * D_ + d;
        float c = cosp[ci], sn = sinp[ci];
        float x1 = bf2f((short)base[d]), x2 = bf2f((short)base[d + 64]);
        base[d]      = f2bf(x1 * c - x2 * sn);
        base[d + 64] = f2bf(x2 * c + x1 * sn);
    }
}

// ---------------- bt-GEMM: C[m][n] = sum_k A[m][k]*Bm[n][k] ----------------
// BM in {128, 64}; BN=128, BK=32, 256 threads (4 waves).
// EPI==0: write f32 C. EPI==1 (BM=128): packed-u32 bf16 scatter into Q0/Kn/Vn.
// Register-lean inner loop (single live B fragment) + launch_bounds(256,4)
// so total regs (incl. AGPR acc) fit 4 waves/SIMD -> 4 blocks/CU, no tail.
template <int BM, int EPI>
__global__ __launch_bounds__(256, 4) void k_gemm(
    const u16* __restrict__ A, const u16* __restrict__ Bm,
    float* __restrict__ Cf, u16* __restrict__ q0p, u16* __restrict__ knp,
    u16* __restrict__ vnp, int M, int N, int K) {
    constexpr int Mi = BM / 32;           // m-frags per wave
    constexpr int NP = (BM + 128) / 64;   // staging pieces per thread
    __shared__ __align__(16) u16 Ash[BM * 32];
    __shared__ __align__(16) u16 Bsh[128 * 32];
    const int tid = threadIdx.x;
    const int w = tid >> 6, lane = tid & 63, quad = lane >> 4, l15 = lane & 15;
    // GROUP_M=8 swizzle: consecutive blocks share the same n-tile (B reuse in L2)
    const int lin = blockIdx.y * gridDim.x + blockIdx.x;
    const int gmsz = 8 * gridDim.x;
    const int grp = lin / gmsz, rem = lin % gmsz;
    const int m0 = (grp * 8 + (rem & 7)) * BM;
    const int n0 = (rem >> 3) * 128;
    const int wm = (w >> 1) * (BM / 2), wn = (w & 1) * 64;

    f32x4 acc[Mi][4];
#pragma unroll
    for (int i = 0; i < Mi; i++)
#pragma unroll
        for (int j = 0; j < 4; j++) acc[i][j] = (f32x4){0.f, 0.f, 0.f, 0.f};

    // staging assignment (16B pieces, XOR-swizzled k-chunk within each row)
    const u16* gsrc[NP];
    u16* ldst[NP];
#pragma unroll
    for (int i = 0; i < NP; i++) {
        int p = tid + i * 256;
        int pw = w * 64 + i * 256;        // wave-uniform first piece
        bool isA = p < BM * 4;
        int pr = isA ? p : p - BM * 4;
        int r = pr >> 2, kc = (pr & 3) ^ ((r >> 1) & 3);
        gsrc[i] = (isA ? A + (size_t)(m0 + r) * K : Bm + (size_t)(n0 + r) * K) + kc * 8;
        ldst[i] = isA ? (Ash + pw * 8) : (Bsh + (pw - BM * 4) * 8);
    }
    // hoisted LDS fragment offsets (u16 elems)
    int aoff[Mi], boff[4];
#pragma unroll
    for (int mi = 0; mi < Mi; mi++) {
        int m = wm + mi * 16 + l15;
        aoff[mi] = (m * 4 + (quad ^ ((m >> 1) & 3))) * 8;
    }
#pragma unroll
    for (int ni = 0; ni < 4; ni++) {
        int n = wn + ni * 16 + l15;
        boff[ni] = (n * 4 + (quad ^ ((n >> 1) & 3))) * 8;
    }

    for (int k0 = 0; k0 < K; k0 += 32) {
#pragma unroll
        for (int i = 0; i < NP; i++) gl_lds16(gsrc[i] + k0, ldst[i]);
        __syncthreads();
        bf16x8 af[Mi];
#pragma unroll
        for (int mi = 0; mi < Mi; mi++) af[mi] = *(const bf16x8*)(Ash + aoff[mi]);
#pragma unroll
        for (int ni = 0; ni < 4; ni++) {
            bf16x8 bb = *(const bf16x8*)(Bsh + boff[ni]);
#pragma unroll
            for (int mi = 0; mi < Mi; mi++)
                acc[mi][ni] = mfma16(af[mi], bb, acc[mi][ni]);
        }
        __syncthreads();
    }

    if constexpr (EPI == 0) {
#pragma unroll
        for (int mi = 0; mi < Mi; mi++)
#pragma unroll
            for (int ni = 0; ni < 4; ni++) {
                int nn = n0 + wn + ni * 16 + l15;
#pragma unroll
                for (int reg = 0; reg < 4; reg++) {
                    int mm = m0 + wm + mi * 16 + quad * 4 + reg;
                    Cf[(size_t)mm * N + nn] = acc[mi][ni][reg];
                }
            }
    } else {
        // packed u32 (2x bf16) scatter into head-major Q/K/V
        const int parity = lane & 1;
        const int bb = m0 >> 11;  // batch (uniform per block; 2048 % 128 == 0)
#pragma unroll
        for (int ni = 0; ni < 4; ni++) {
            int nn0 = n0 + wn + ni * 16;     // wave-uniform
            int nh = nn0 >> 7;
            u16* hp;
            if (nh < 16)      hp = q0p + (size_t)(bb * H_ + nh) * S_ * D_;
            else if (nh < 24) hp = knp + (size_t)(bb * KVH_ + (nh - 16)) * S_ * D_;
            else              hp = vnp + (size_t)(bb * KVH_ + (nh - 24)) * S_ * D_;
            int d = (nn0 & 127) + (l15 & ~1);
#pragma unroll
            for (int mi = 0; mi < Mi; mi++) {
#pragma unroll
                for (int j = 0; j < 2; j++) {
                    int myreg = parity * 2 + j;
                    int sendreg = (1 - parity) * 2 + j;
                    float mine = acc[mi][ni][myreg];
                    float recv = __shfl_xor(acc[mi][ni][sendreg], 1);
                    float lo = parity ? recv : mine;
                    float hi = parity ? mine : recv;
                    u32 pk = (u32)f2bf(lo) | ((u32)f2bf(hi) << 16);
                    int mm = m0 + wm + mi * 16 + quad * 4 + parity * 2 + j;
                    int ss = mm & (S_ - 1);
                    *(u32*)(hp + (size_t)ss * D_ + d) = pk;
                }
            }
        }
    }
}

// ---------------- flash attention + 3 diagonal extra keys ------------------
// Double-buffered K/V staging with raw s_waitcnt vmcnt(4)+s_barrier so the
// prefetch stays in flight across the barrier (AITER-style), longest-q0-first
// dispatch order, lane-partial l accumulation (one final reduction).
__global__ __launch_bounds__(256) void k_attn(
    const u16* __restrict__ Q0, const u16* __restrict__ K0c, const u16* __restrict__ V0T,
    const u16* __restrict__ Kn, const u16* __restrict__ Vn,
    const float* __restrict__ ck, const float* __restrict__ cv,
    u16* __restrict__ AO) {
    __shared__ __align__(16) u16 Ksh[2 * 4096];    // 2 bufs x (32 j x 128 d)
    __shared__ __align__(16) u16 VTsh[2 * 4096];   // 2 bufs x (128 d x 32 j)
    __shared__ __align__(16) u16 Psh[4 * 16 * 40]; // per-wave 16 x 32, stride 40
    __shared__ float esh[4 * 48];
    const int tid = threadIdx.x, w = tid >> 6, lane = tid & 63;
    const int quad = lane >> 4, l15 = lane & 15;
    const int b = blockIdx.x >> 4, h = blockIdx.x & 15;
    const int q0 = (31 - blockIdx.y) * 64;   // longest blocks dispatch first
    const int bh = b * H_ + h;
    const size_t kbase = (size_t)bh * S_ * D_;

    bf16x8 qf[4];
    {
        const u16* qp = Q0 + kbase + (size_t)(q0 + w * 16 + l15) * D_;
#pragma unroll
        for (int t = 0; t < 4; t++) qf[t] = *(const bf16x8*)(qp + t * 32 + quad * 8);
    }
    f32x4 Ot[8];
#pragma unroll
    for (int t = 0; t < 8; t++) Ot[t] = (f32x4){0.f, 0.f, 0.f, 0.f};
    float mrow[4] = {-1e30f, -1e30f, -1e30f, -1e30f};
    float lrow[4] = {0.f, 0.f, 0.f, 0.f};  // lane-partial (per 2 keys/lane)

    int pA = tid, pB = tid + 256;
    int kj0 = pA >> 4, kc0 = (pA & 15) ^ ((kj0 >> 1) & 7);
    int kj1 = pB >> 4, kc1 = (pB & 15) ^ ((kj1 >> 1) & 7);
    int vd0 = pA >> 2, vq0 = (pA & 3) ^ ((vd0 >> 1) & 3);
    int vd1 = pB >> 2, vq1 = (pB & 3) ^ ((vd1 >> 1) & 3);
    const u16* kg0 = K0c + kbase + (size_t)kj0 * D_ + kc0 * 8;
    const u16* kg1 = K0c + kbase + (size_t)kj1 * D_ + kc1 * 8;
    const u16* vg0 = V0T + kbase + (size_t)vd0 * S_ + vq0 * 8;
    const u16* vg1 = V0T + kbase + (size_t)vd1 * S_ + vq1 * 8;
    const int ofsA = w * 512, ofsB = 2048 + w * 512;  // per-wave LDS piece bases

    const int ntiles = (q0 >> 5) + 2;
    // prologue: stage tile 0 into buffer 0
    gl_lds16(kg0, Ksh + ofsA);
    gl_lds16(kg1, Ksh + ofsB);
    gl_lds16(vg0, VTsh + ofsA);
    gl_lds16(vg1, VTsh + ofsB);

    for (int jt = 0; jt < ntiles; ++jt) {
        const int cur = jt & 1;
        const u16* Kb = Ksh + cur * 4096;
        const u16* Vb = VTsh + cur * 4096;
        if (jt + 1 < ntiles) {
            const int nb = (cur ^ 1) * 4096;
            const size_t j1 = (size_t)(jt + 1) * 32;
            gl_lds16(kg0 + j1 * D_, Ksh + nb + ofsA);
            gl_lds16(kg1 + j1 * D_, Ksh + nb + ofsB);
            gl_lds16(vg0 + j1, VTsh + nb + ofsA);
            gl_lds16(vg1 + j1, VTsh + nb + ofsB);
            // wait only for CURRENT tile's 4 loads; keep the 4 prefetch in flight
            __asm__ volatile("s_waitcnt vmcnt(4)\n\ts_barrier" ::: "memory");
        } else {
            __asm__ volatile("s_waitcnt vmcnt(0)\n\ts_barrier" ::: "memory");
        }
        const int j0 = jt * 32;

        f32x4 s0 = (f32x4){0.f, 0.f, 0.f, 0.f}, s1 = (f32x4){0.f, 0.f, 0.f, 0.f};
#pragma unroll
        for (int t = 0; t < 4; t++) {
            int kc = t * 4 + quad;
            bf16x8 k0f = *(const bf16x8*)(Kb + (l15 * 16 + (kc ^ ((l15 >> 1) & 7))) * 8);
            int j1i = l15 + 16;
            bf16x8 k1f = *(const bf16x8*)(Kb + (j1i * 16 + (kc ^ ((j1i >> 1) & 7))) * 8);
            s0 = mfma16(qf[t], k0f, s0);
            s1 = mfma16(qf[t], k1f, s1);
        }
        if (j0 + 31 > q0 + w * 16) {  // causal mask on diagonal-crossing tiles
#pragma unroll
            for (int reg = 0; reg < 4; reg++) {
                int r = q0 + w * 16 + quad * 4 + reg;
                if (j0 + l15 > r) s0[reg] = -1e30f;
                if (j0 + 16 + l15 > r) s1[reg] = -1e30f;
            }
        }
        float pr0[4], pr1[4], alpha[4];
        int changed = 0;
#pragma unroll
        for (int reg = 0; reg < 4; reg++) {
            float tm = fmaxf(s0[reg], s1[reg]);
            tm = fmaxf(tm, __shfl_xor(tm, 1));
            tm = fmaxf(tm, __shfl_xor(tm, 2));
            tm = fmaxf(tm, __shfl_xor(tm, 4));
            tm = fmaxf(tm, __shfl_xor(tm, 8));
            if (tm > mrow[reg]) {
                changed = 1;
                alpha[reg] = __expf(mrow[reg] - tm);
                mrow[reg] = tm;
            } else {
                alpha[reg] = 1.f;
            }
            pr0[reg] = __expf(s0[reg] - mrow[reg]);
            pr1[reg] = __expf(s1[reg] - mrow[reg]);
            lrow[reg] = lrow[reg] * alpha[reg] + pr0[reg] + pr1[reg];
        }
        if (__any(changed)) {
#pragma unroll
            for (int t = 0; t < 8; t++)
#pragma unroll
                for (int reg = 0; reg < 4; reg++) Ot[t][reg] *= alpha[reg];
        }

        // P: C-layout -> LDS -> A-fragment layout (padded stride 40 elems)
        u16* pb = Psh + w * 640;
#pragma unroll
        for (int reg = 0; reg < 4; reg++) {
            int r = quad * 4 + reg;
            pb[r * 40 + l15] = f2bf(pr0[reg]);
            pb[r * 40 + 16 + l15] = f2bf(pr1[reg]);
        }
        bf16x8 pa = *(const bf16x8*)(pb + l15 * 40 + quad * 8);
#pragma unroll
        for (int t = 0; t < 8; t++) {
            int d = t * 16 + l15;
            bf16x8 vb = *(const bf16x8*)(Vb + (d * 4 + (quad ^ ((d >> 1) & 3))) * 8);
            Ot[t] = mfma16(pa, vb, Ot[t]);
        }
        // end-of-iter barrier WITHOUT vmcnt drain (prefetch stays in flight)
        __asm__ volatile("s_barrier" ::: "memory");
    }

    // final cross-lane reduction of l (deferred from per-tile)
    float lsum[4];
#pragma unroll
    for (int reg = 0; reg < 4; reg++) {
        float r = lrow[reg];
        r += __shfl_xor(r, 1);
        r += __shfl_xor(r, 2);
        r += __shfl_xor(r, 4);
        r += __shfl_xor(r, 8);
        lsum[reg] = r;
    }

    // ---- extras: 3 diagonal keys/values per row ----
    const int srow_a = q0 + w * 16 + l15;  // A-layout row of this lane
    float ev[3];
#pragma unroll
    for (int c = 0; c < 2; c++) {
        const float* kp = ck + ((size_t)((1 + c) * B_ + b) * H_ + h) * S_ * D_ + (size_t)srow_a * D_;
        float part = 0.f;
#pragma unroll
        for (int t = 0; t < 4; t++) {
            int dbase = t * 32 + quad * 8;
            float4 v0 = *(const float4*)(kp + dbase);
            float4 v1 = *(const float4*)(kp + dbase + 4);
            part += bf2f(qf[t][0]) * v0.x + bf2f(qf[t][1]) * v0.y +
                    bf2f(qf[t][2]) * v0.z + bf2f(qf[t][3]) * v0.w;
            part += bf2f(qf[t][4]) * v1.x + bf2f(qf[t][5]) * v1.y +
                    bf2f(qf[t][6]) * v1.z + bf2f(qf[t][7]) * v1.w;
        }
        part += __shfl_xor(part, 16);
        part += __shfl_xor(part, 32);
        ev[c] = part;
    }
    {
        const u16* kp = Kn + ((size_t)(b * KVH_ + (h >> 1)) * S_ + srow_a) * D_;
        float part = 0.f;
#pragma unroll
        for (int t = 0; t < 4; t++) {
            bf16x8 kv = *(const bf16x8*)(kp + t * 32 + quad * 8);
#pragma unroll
            for (int i = 0; i < 8; i++) part += bf2f(qf[t][i]) * bf2f(kv[i]);
        }
        part += __shfl_xor(part, 16);
        part += __shfl_xor(part, 32);
        ev[2] = part;
    }
    if (quad == 0) {
        esh[w * 48 + l15] = ev[0];
        esh[w * 48 + 16 + l15] = ev[1];
        esh[w * 48 + 32 + l15] = ev[2];
    }
    __syncthreads();

    float alr[4], w0r[4], w1r[4], w2r[4], invr[4];
#pragma unroll
    for (int reg = 0; reg < 4; reg++) {
        int r = quad * 4 + reg;
        float e0 = esh[w * 48 + r], e1 = esh[w * 48 + 16 + r], e2 = esh[w * 48 + 32 + r];
        float mn = fmaxf(fmaxf(mrow[reg], e0), fmaxf(e1, e2));
        alr[reg] = __expf(mrow[reg] - mn);
        w0r[reg] = __expf(e0 - mn);
        w1r[reg] = __expf(e1 - mn);
        w2r[reg] = __expf(e2 - mn);
        float lf = lsum[reg] * alr[reg] + w0r[reg] + w1r[reg] + w2r[reg];
        invr[reg] = 1.f / lf;
    }
    const float* v1p = cv + ((size_t)(B_ + b) * H_ + h) * S_ * D_;       // layer 1
    const float* v2p = cv + ((size_t)(2 * B_ + b) * H_ + h) * S_ * D_;   // layer 2
    const u16* vnp = Vn + ((size_t)(b * KVH_ + (h >> 1))) * S_ * D_;
#pragma unroll
    for (int t = 0; t < 8; t++) {
        int d = t * 16 + l15;
#pragma unroll
        for (int reg = 0; reg < 4; reg++) {
            int sr = q0 + w * 16 + quad * 4 + reg;
            float v1 = v1p[(size_t)sr * D_ + d];
            float v2 = v2p[(size_t)sr * D_ + d];
            float vn = bf2f((short)vnp[(size_t)sr * D_ + d]);
            float o = (Ot[t][reg] * alr[reg] + w0r[reg] * v1 + w1r[reg] * v2 + w2r[reg] * vn) * invr[reg];
            AO[((size_t)(b * S_ + sr)) * HID_ + h * D_ + d] = f2bf(o);
        }
    }
}

// ---------------------------------------------------------------------------
extern "C" void kernel_launch(void* const* d_in, const int* in_sizes, int n_in,
                              void* d_out, int out_size, void* d_ws, size_t ws_size,
                              hipStream_t stream) {
    const float* hs      = (const float*)d_in[0];
    const float* cosp    = (const float*)d_in[2];
    const float* sinp    = (const float*)d_in[3];
    const float* cache_k = (const float*)d_in[4];
    const float* cache_v = (const float*)d_in[5];
    const float* Wq      = (const float*)d_in[6];
    const float* Wk      = (const float*)d_in[7];
    const float* Wv      = (const float*)d_in[8];
    const float* Wo      = (const float*)d_in[9];
    float* out = (float*)d_out;

    u16* ws = (u16*)d_ws;
    // Region A (32MB): X16 [conv->gemm1], then AO [attn->gemm2]
    u16* X16  = ws;
    u16* AO   = ws;
    // Region B (32MB): Wqkv16 [conv->gemm1], then K0c + V0T [conv->attn]
    u16* Wqkv = ws + 16777216;
    u16* K0c  = ws + 16777216;
    u16* V0T  = ws + 25165824;
    u16* Wo16 = ws + 33554432;  // 8MB
    u16* Q0   = ws + 37748736;  // 16MB
    u16* Kn   = ws + 46137344;  // 8MB
    u16* Vn   = ws + 50331648;  // 8MB

    // conversions
    k_conv<<<16384, 256, 0, stream>>>(hs, X16, 4194304);
    k_convw<<<20480, 256, 0, stream>>>(Wq, Wk, Wv, Wo,
                                       Wqkv, Wqkv + 8388608, Wqkv + 12582912, Wo16);

    // QKV projection with head-major packed scatter epilogue
    k_gemm<128, 1><<<dim3(32, 32), 256, 0, stream>>>(X16, Wqkv, nullptr, Q0, Kn, Vn,
                                                     4096, 4096, 4096);
    // RoPE (Q pre-scaled by 1/sqrt(D))
    k_rope<<<24576, 256, 0, stream>>>(Q0, Kn, cosp, sinp);

    // cache layer-0 conversions (into region B, now dead)
    k_conv<<<8192, 256, 0, stream>>>(cache_k, K0c, 2097152);
    k_vtrans<<<dim3(64, 4, 32), 256, 0, stream>>>(cache_v, V0T);

    // flash attention + extras (x = bh, y = reversed q-block: longest first)
    k_attn<<<dim3(32, 32), 256, 0, stream>>>(Q0, K0c, V0T, Kn, Vn,
                                             cache_k, cache_v, AO);
    // output projection: 64x128 tiles -> 1024 blocks (full residency)
    k_gemm<64, 0><<<dim3(16, 64), 256, 0, stream>>>(AO, Wo16, out, nullptr, nullptr,
                                                    nullptr, 4096, 2048, 2048);
}